// Round 9
// baseline (1134.728 us; speedup 1.0000x reference)
//
#include <hip/hip_runtime.h>
#include <stdint.h>

// ---- problem constants ----
#define B_ 2
#define T_ 2048
#define D_ 512
#define H_ 8
#define HD_ 64
#define V_ 32000
#define L_ 4
#define NL_ 3
#define HID_ 2048
#define NROW 4096          // B*T
#define CCH 64             // chunk timesteps
#define CROWS 128          // rows per chunk (CCH*B)
#define NC 32              // T/CCH
#define EPS_ 1e-5f

typedef __attribute__((ext_vector_type(8))) __bf16 bf16x8;
typedef __attribute__((ext_vector_type(4))) float f32x4;

__device__ __forceinline__ float b2f(unsigned short u) {
  union { uint32_t i; float f; } v; v.i = ((uint32_t)u) << 16; return v.f;
}
__device__ __forceinline__ unsigned short f2b(float f) {
  union { float f; uint32_t i; } v; v.f = f;
  uint32_t u = v.i;
  u += 0x7fffu + ((u >> 16) & 1u);   // RNE
  return (unsigned short)(u >> 16);
}

// ================= mega-prep: weights + embed + layer-0 LN1 + cnt-zero ======
// sections: [0,4096) qkvo-T, [4096,16384) W1T, [16384,28672) W2cat,
// [28672,44672) emb cvt, [44672,46720) embed+LN1(l=0), [46720,46728) bsum,
// [46728] zero attn counters.  Total 46729.
__global__ __launch_bounds__(256) void k_prep(
    const float* __restrict__ emb, const float* __restrict__ pos,
    const int* __restrict__ ids,
    const float* __restrict__ Wq, const float* __restrict__ Wk,
    const float* __restrict__ Wv, const float* __restrict__ Wo,
    const float* __restrict__ W1, const float* __restrict__ W2,
    const float* __restrict__ b2,
    const float* __restrict__ ln1g, const float* __restrict__ ln1b,
    unsigned short* __restrict__ WqkvT, unsigned short* __restrict__ WoT,
    unsigned short* __restrict__ W1T, unsigned short* __restrict__ W2cat,
    unsigned short* __restrict__ embB, float* __restrict__ bsum,
    float* __restrict__ x, unsigned short* __restrict__ h,
    int* __restrict__ cnt) {
  int bid = blockIdx.x, tid = threadIdx.x;
  __shared__ float tile[32][33];
  __shared__ float red[4], red2[4];
  int tx = tid & 31, ty = tid >> 5;
  if (bid < 4096) {                       // Wq/Wk/Wv (z=l*3+m) + Wo transpose
    int z = bid >> 8, r = bid & 255;
    int bx = (r & 15) * 32, by = (r >> 4) * 32;
    const float* in; unsigned short* out;
    if (z < 12) {
      int l = z / 3, m = z - l * 3;
      in = (m == 0 ? Wq : m == 1 ? Wk : Wv) + (size_t)l * D_ * D_;
      out = WqkvT + (size_t)z * D_ * D_;
    } else {
      in = Wo + (size_t)(z - 12) * D_ * D_;
      out = WoT + (size_t)(z - 12) * D_ * D_;
    }
#pragma unroll
    for (int i = 0; i < 4; i++)
      tile[ty + 8 * i][tx] = in[(size_t)(by + ty + 8 * i) * D_ + bx + tx];
    __syncthreads();
#pragma unroll
    for (int i = 0; i < 4; i++)
      out[(size_t)(bx + ty + 8 * i) * D_ + by + tx] = f2b(tile[tx][ty + 8 * i]);
  } else if (bid < 16384) {               // W1 [z][512][2048] -> W1T [z][2048][512]
    int s = bid - 4096;
    int z = s >> 10, r = s & 1023;
    int bx = (r & 63) * 32, by = (r >> 6) * 32;
    const float* in = W1 + (size_t)z * D_ * HID_;
    unsigned short* out = W1T + (size_t)z * HID_ * D_;
#pragma unroll
    for (int i = 0; i < 4; i++)
      tile[ty + 8 * i][tx] = in[(size_t)(by + ty + 8 * i) * HID_ + bx + tx];
    __syncthreads();
#pragma unroll
    for (int i = 0; i < 4; i++)
      out[(size_t)(bx + ty + 8 * i) * D_ + by + tx] = f2b(tile[tx][ty + 8 * i]);
  } else if (bid < 28672) {               // W2 [z][2048][512] -> W2cat[l][d][n*2048+k]
    int s = bid - 16384;
    int z = s >> 10, r = s & 1023;
    int l = z / 3, n = z - l * 3;
    int bx = (r & 15) * 32, by = (r >> 4) * 32;   // bx: d, by: k
    const float* in = W2 + (size_t)z * HID_ * D_;
#pragma unroll
    for (int i = 0; i < 4; i++)
      tile[ty + 8 * i][tx] = in[(size_t)(by + ty + 8 * i) * D_ + bx + tx];
    __syncthreads();
#pragma unroll
    for (int i = 0; i < 4; i++)
      W2cat[((size_t)l * D_ + bx + ty + 8 * i) * (NL_ * HID_) + n * HID_ + by + tx] =
          f2b(tile[tx][ty + 8 * i]);
  } else if (bid < 44672) {               // emb f32 -> bf16
    int s = bid - 28672;
    int base = (s * 256 + tid) * 4;
    float4 v = *(const float4*)(emb + base);
    unsigned short o[4] = { f2b(v.x), f2b(v.y), f2b(v.z), f2b(v.w) };
    *(uint2*)(embB + base) = *(const uint2*)o;
  } else if (bid < 46720) {               // embed + LN1(layer0): 2 rows per block
    int s = bid - 44672;
    int i = s * 256 + tid;
    int row = i >> 7, cg = i & 127;
    int t = row & (T_ - 1);
    int id = ids[row];
    float4 e = ((const float4*)(emb + (size_t)id * D_))[cg];
    float4 p = ((const float4*)(pos + (size_t)t * D_))[cg];
    float4 xv; xv.x = e.x + p.x; xv.y = e.y + p.y; xv.z = e.z + p.z; xv.w = e.w + p.w;
    ((float4*)(x + (size_t)row * D_))[cg] = xv;
    float sum = xv.x + xv.y + xv.z + xv.w;
#pragma unroll
    for (int o = 32; o >= 1; o >>= 1) sum += __shfl_xor(sum, o);
    int wv = tid >> 6;
    if ((tid & 63) == 0) red[wv] = sum;
    __syncthreads();
    int wb = (tid >> 7) * 2;
    float mu = (red[wb] + red[wb + 1]) * (1.f / D_);
    float dx = xv.x - mu, dy = xv.y - mu, dz = xv.z - mu, dw = xv.w - mu;
    float s2 = dx * dx + dy * dy + dz * dz + dw * dw;
#pragma unroll
    for (int o = 32; o >= 1; o >>= 1) s2 += __shfl_xor(s2, o);
    if ((tid & 63) == 0) red2[wv] = s2;
    __syncthreads();
    float var = (red2[wb] + red2[wb + 1]) * (1.f / D_);
    float rs = rsqrtf(var + EPS_);
    float4 gv = ((const float4*)ln1g)[cg];
    float4 bv = ((const float4*)ln1b)[cg];
    unsigned short o4[4] = { f2b(dx * rs * gv.x + bv.x), f2b(dy * rs * gv.y + bv.y),
                             f2b(dz * rs * gv.z + bv.z), f2b(dw * rs * gv.w + bv.w) };
    *(uint2*)(h + (size_t)row * D_ + cg * 4) = *(const uint2*)o4;
  } else if (bid < 46728) {               // bsum
    int s = bid - 46720;
    int l = s >> 1, d = (s & 1) * 256 + tid;
    float acc = 0.f;
#pragma unroll
    for (int n = 0; n < NL_; n++) acc += b2[((size_t)l * NL_ + n) * D_ + d];
    bsum[(size_t)l * D_ + d] = acc;
  } else {                                // zero attn counters (L*H = 32)
    if (tid < L_ * H_) cnt[tid] = 0;
  }
}

// ---- layernorm (LN2): f32 row -> bf16 row ----
__global__ __launch_bounds__(128) void k_ln(
    const float* __restrict__ x, const float* __restrict__ g,
    const float* __restrict__ b, unsigned short* __restrict__ out) {
  int row = blockIdx.x;
  int tid = threadIdx.x;
  const float* xr = x + (size_t)row * D_;
  float4 v = ((const float4*)xr)[tid];
  float s = v.x + v.y + v.z + v.w;
#pragma unroll
  for (int o = 32; o >= 1; o >>= 1) s += __shfl_xor(s, o);
  __shared__ float red[2], red2[2];
  int wv = tid >> 6;
  if ((tid & 63) == 0) red[wv] = s;
  __syncthreads();
  float mu = (red[0] + red[1]) * (1.f / D_);
  float dx = v.x - mu, dy = v.y - mu, dz = v.z - mu, dw = v.w - mu;
  float s2 = dx * dx + dy * dy + dz * dz + dw * dw;
#pragma unroll
  for (int o = 32; o >= 1; o >>= 1) s2 += __shfl_xor(s2, o);
  if ((tid & 63) == 0) red2[wv] = s2;
  __syncthreads();
  float var = (red2[0] + red2[1]) * (1.f / D_);
  float rs = rsqrtf(var + EPS_);
  float4 gv = ((const float4*)g)[tid];
  float4 bv = ((const float4*)b)[tid];
  unsigned short o4[4] = { f2b(dx * rs * gv.x + bv.x), f2b(dy * rs * gv.y + bv.y),
                           f2b(dz * rs * gv.z + bv.z), f2b(dw * rs * gv.w + bv.w) };
  *(uint2*)(out + (size_t)row * D_ + tid * 4) = *(const uint2*)o4;
}

// ---- cms reduce + next LN fused ----
__global__ __launch_bounds__(256) void k_cmsred_ln(
    float* __restrict__ x, const float* __restrict__ parts,
    const float* __restrict__ bsum, const float* __restrict__ g,
    const float* __restrict__ b, unsigned short* __restrict__ h) {
  int bid = blockIdx.x, tid = threadIdx.x;
  int row = bid * 2 + (tid >> 7);
  int cg = tid & 127;
  size_t base = (size_t)row * D_ + cg * 4;
  float4 xv = *(const float4*)(x + base);
  float4 p0 = *(const float4*)(parts + base);
  float4 p1 = *(const float4*)(parts + (size_t)NROW * D_ + base);
  float4 p2 = *(const float4*)(parts + 2ull * NROW * D_ + base);
  float4 bs = *(const float4*)(bsum + cg * 4);
  const float k3 = 1.f / 3.f;
  xv.x += (p0.x + p1.x + p2.x + bs.x) * k3;
  xv.y += (p0.y + p1.y + p2.y + bs.y) * k3;
  xv.z += (p0.z + p1.z + p2.z + bs.z) * k3;
  xv.w += (p0.w + p1.w + p2.w + bs.w) * k3;
  *(float4*)(x + base) = xv;
  float sum = xv.x + xv.y + xv.z + xv.w;
#pragma unroll
  for (int o = 32; o >= 1; o >>= 1) sum += __shfl_xor(sum, o);
  __shared__ float red[4], red2[4];
  int wv = tid >> 6;
  if ((tid & 63) == 0) red[wv] = sum;
  __syncthreads();
  int wb = (tid >> 7) * 2;
  float mu = (red[wb] + red[wb + 1]) * (1.f / D_);
  float dx = xv.x - mu, dy = xv.y - mu, dz = xv.z - mu, dw = xv.w - mu;
  float s2 = dx * dx + dy * dy + dz * dz + dw * dw;
#pragma unroll
  for (int o = 32; o >= 1; o >>= 1) s2 += __shfl_xor(s2, o);
  if ((tid & 63) == 0) red2[wv] = s2;
  __syncthreads();
  float var = (red2[wb] + red2[wb + 1]) * (1.f / D_);
  float rs = rsqrtf(var + EPS_);
  float4 gv = ((const float4*)g)[cg];
  float4 bv = ((const float4*)b)[cg];
  unsigned short o4[4] = { f2b(dx * rs * gv.x + bv.x), f2b(dy * rs * gv.y + bv.y),
                           f2b(dz * rs * gv.z + bv.z), f2b(dw * rs * gv.w + bv.w) };
  *(uint2*)(h + base) = *(const uint2*)o4;
}

// ================= GEMM templates =================
enum { E_QKV = 0, E_RES = 1, E_GELU = 2, E_PART = 3, E_F32 = 4 };

// stage a TRx64 bf16 tile, source-side XOR swizzle, gload_lds w16
template <int TR, int NW>
__device__ __forceinline__ void stage_tile(
    const unsigned short* __restrict__ gbase, int ldk, unsigned short* lds,
    int wave, int lane) {
#pragma unroll
  for (int q = 0; q < 4; q++) {
    int Lb = (q * NW + wave) << 10;             // wave-uniform LDS byte base
    int L = Lb + lane * 16;
    int row = L >> 7;
    int colb = (L & 127) ^ ((row & 7) << 4);    // involutive swizzle
    const unsigned short* gsrc = gbase + (size_t)row * ldk + (colb >> 1);
    __builtin_amdgcn_global_load_lds(
        (const __attribute__((address_space(1))) uint32_t*)gsrc,
        (__attribute__((address_space(3))) uint32_t*)(lds + (Lb >> 1)),
        16, 0, 0);
  }
}

// ---- 128x128 tile, 2-phase prologue-prefetch double-buffer ----
template <int EPI>
__global__ __launch_bounds__(256, 2) void k_gemm128(
    const unsigned short* __restrict__ A,   // [M][ldk] bf16
    const unsigned short* __restrict__ Bt,  // [N][ldk] bf16
    const float* __restrict__ bias,
    void* __restrict__ Out,
    int Kext, int ldk, int N, int ldOut) {
  int z = blockIdx.z;
  A  += (size_t)z * Kext;                  // split-K column offset
  Bt += (size_t)z * Kext;
  int lane = threadIdx.x & 63, wave = threadIdx.x >> 6;
  int wm = wave >> 1, wn = wave & 1;
  int bx = blockIdx.x, by = blockIdx.y;

  __shared__ __align__(16) unsigned short As[2][128 * 64];
  __shared__ __align__(16) unsigned short Bs[2][128 * 64];

  const unsigned short* Ab = A + (size_t)by * 128 * ldk;
  const unsigned short* Bb = Bt + (size_t)bx * 128 * ldk;

  f32x4 acc[4][4] = {};
  int nk = Kext / 64;
  stage_tile<128, 4>(Ab, ldk, As[0], wave, lane);
  stage_tile<128, 4>(Bb, ldk, Bs[0], wave, lane);
  __syncthreads();
  for (int kt = 0; kt < nk; kt++) {
    int cur = kt & 1;
    if (kt + 1 < nk) {                     // issue next tile BEFORE compute
      stage_tile<128, 4>(Ab + (size_t)(kt + 1) * 64, ldk, As[cur ^ 1], wave, lane);
      stage_tile<128, 4>(Bb + (size_t)(kt + 1) * 64, ldk, Bs[cur ^ 1], wave, lane);
    }
    const char* Ac = (const char*)As[cur];
    const char* Bc = (const char*)Bs[cur];
#pragma unroll
    for (int kk = 0; kk < 2; kk++) {
      bf16x8 af[4], bfr[4];
#pragma unroll
      for (int mt = 0; mt < 4; mt++) {
        int row = wm * 64 + mt * 16 + (lane & 15);
        int off = ((row << 7) | (kk * 64 + ((lane >> 4) << 4))) ^ ((row & 7) << 4);
        af[mt] = *(const bf16x8*)(Ac + off);
      }
#pragma unroll
      for (int nt = 0; nt < 4; nt++) {
        int row = wn * 64 + nt * 16 + (lane & 15);
        int off = ((row << 7) | (kk * 64 + ((lane >> 4) << 4))) ^ ((row & 7) << 4);
        bfr[nt] = *(const bf16x8*)(Bc + off);
      }
#pragma unroll
      for (int mt = 0; mt < 4; mt++)
#pragma unroll
        for (int nt = 0; nt < 4; nt++)
          acc[mt][nt] = __builtin_amdgcn_mfma_f32_16x16x32_bf16(
              af[mt], bfr[nt], acc[mt][nt], 0, 0, 0);
    }
    __syncthreads();   // drains vmcnt: next tile landed while we computed
  }

  int gm = by * 128 + wm * 64;
  int gn = bx * 128 + wn * 64;
#pragma unroll
  for (int mt = 0; mt < 4; mt++) {
#pragma unroll
    for (int nt = 0; nt < 4; nt++) {
      int m0 = gm + mt * 16 + ((lane >> 4) << 2);
      int n = gn + nt * 16 + (lane & 15);
#pragma unroll
      for (int j = 0; j < 4; j++) {
        float v = acc[mt][nt][j];
        int m = m0 + j;
        if constexpr (EPI == E_QKV) {          // N=1536 -> qkv[zq][row][col]
          int zq = n >> 9, col = n & 511;
          ((unsigned short*)Out)[((size_t)zq * NROW + m) * D_ + col] = f2b(v);
        } else if constexpr (EPI == E_RES) {   // x = resid + v
          size_t idx = (size_t)m * ldOut + n;
          ((float*)Out)[idx] = bias[idx] + v;
        } else {                               // E_PART: parts[z][m][n]
          ((float*)Out)[(size_t)z * NROW * D_ + (size_t)m * ldOut + n] = v;
        }
      }
    }
  }
}

// ---- 256x256x64, 8 waves, single-buffer (2 blk/CU co-residency) ----
template <int EPI>
__global__ __launch_bounds__(512) void k_gemm256(
    const unsigned short* __restrict__ A,
    const unsigned short* __restrict__ Bt,
    const float* __restrict__ bias,
    void* __restrict__ Out,
    int K, int N, int ldOut) {
  int lane = threadIdx.x & 63, wave = threadIdx.x >> 6;   // 8 waves
  int wm = wave >> 2, wn = wave & 3;
  int bx = blockIdx.x, by = blockIdx.y;
  if constexpr (EPI == E_F32) {
    // supertile remap: 25 bx x 16 by groups for B-panel L2/L3 reuse (gridDim.x=125)
    int lin = blockIdx.y * 125 + blockIdx.x;
    int seg = lin / 400, rem = lin % 400;
    bx = seg * 25 + rem % 25;  by = rem / 25;
  }

  __shared__ __align__(16) unsigned short As[256 * 64];
  __shared__ __align__(16) unsigned short Bs[256 * 64];

  const unsigned short* Ab = A + (size_t)by * 256 * K;
  const unsigned short* Bb = Bt + (size_t)bx * 256 * K;

  f32x4 acc[8][4] = {};
  int nk = K / 64;
  for (int kt = 0; kt < nk; kt++) {
    stage_tile<256, 8>(Ab + (size_t)kt * 64, K, As, wave, lane);
    stage_tile<256, 8>(Bb + (size_t)kt * 64, K, Bs, wave, lane);
    __syncthreads();
    const char* Ac = (const char*)As;
    const char* Bc = (const char*)Bs;
#pragma unroll
    for (int kk = 0; kk < 2; kk++) {
      bf16x8 af[8], bfr[4];
#pragma unroll
      for (int mt = 0; mt < 8; mt++) {
        int row = wm * 128 + mt * 16 + (lane & 15);
        int off = ((row << 7) | (kk * 64 + ((lane >> 4) << 4))) ^ ((row & 7) << 4);
        af[mt] = *(const bf16x8*)(Ac + off);
      }
#pragma unroll
      for (int nt = 0; nt < 4; nt++) {
        int row = wn * 64 + nt * 16 + (lane & 15);
        int off = ((row << 7) | (kk * 64 + ((lane >> 4) << 4))) ^ ((row & 7) << 4);
        bfr[nt] = *(const bf16x8*)(Bc + off);
      }
#pragma unroll
      for (int mt = 0; mt < 8; mt++)
#pragma unroll
        for (int nt = 0; nt < 4; nt++)
          acc[mt][nt] = __builtin_amdgcn_mfma_f32_16x16x32_bf16(
              af[mt], bfr[nt], acc[mt][nt], 0, 0, 0);
    }
    __syncthreads();
  }

  int gm = by * 256 + wm * 128;
  int gn = bx * 256 + wn * 64;
#pragma unroll
  for (int mt = 0; mt < 8; mt++) {
#pragma unroll
    for (int nt = 0; nt < 4; nt++) {
      int m0 = gm + mt * 16 + ((lane >> 4) << 2);
      int n = gn + nt * 16 + (lane & 15);
#pragma unroll
      for (int j = 0; j < 4; j++) {
        float v = acc[mt][nt][j];
        size_t idx = (size_t)(m0 + j) * ldOut + n;
        if constexpr (EPI == E_GELU) {
          v += bias[n];
          float u2 = 1.5957691216057308f * (v + 0.044715f * v * v * v);
          float sg = 1.f / (1.f + __expf(-u2));   // tanh-approx GELU
          ((unsigned short*)Out)[idx] = f2b(v * sg);
        } else {                                  // E_F32 (head)
          ((float*)Out)[idx] = v;
        }
      }
    }
  }
}

// ================= fused attention: A(outer-products) -> barrier -> prefix+C ==
__device__ __forceinline__ void unpack8f(uint4 u, float* dst) {
  dst[0] = b2f((unsigned short)(u.x & 0xffff)); dst[1] = b2f((unsigned short)(u.x >> 16));
  dst[2] = b2f((unsigned short)(u.y & 0xffff)); dst[3] = b2f((unsigned short)(u.y >> 16));
  dst[4] = b2f((unsigned short)(u.z & 0xffff)); dst[5] = b2f((unsigned short)(u.z >> 16));
  dst[6] = b2f((unsigned short)(u.w & 0xffff)); dst[7] = b2f((unsigned short)(u.w >> 16));
}

// grid (NC, H) = 256 blocks <= 256 CUs -> all co-resident; device-scope
// atomic barrier per head (G16 pattern). 64 KB LDS reused across phases.
__global__ __launch_bounds__(256) void k_attn(
    const unsigned short* __restrict__ qbuf, const unsigned short* __restrict__ kbuf,
    const unsigned short* __restrict__ vbuf, float* __restrict__ G,
    int* __restrict__ cnt, unsigned short* __restrict__ ybuf) {
  int c = blockIdx.x, h = blockIdx.y;
  __shared__ __align__(16) char sm_raw[65536];
  int tid = threadIdx.x, lane = tid & 63, w = tid >> 6;

  // ---------------- phase A: G[c,h,d,k] = 0.5 * sum_rows v_d * k_k ----------
  {
    float (*Ks)[HD_] = (float(*)[HD_])sm_raw;            // [128][64] f32
    float (*Vs)[HD_] = (float(*)[HD_])(sm_raw + 32768);  // [128][64] f32
#pragma unroll
    for (int it = 0; it < 4; it++) {
      int gi = it * 256 + tid;
      int r = gi >> 3, c8 = gi & 7;
      int bb = r & 1, tt = c * CCH + (r >> 1);
      size_t goff = ((size_t)bb * T_ + tt) * D_ + h * HD_ + c8 * 8;
      uint4 kv = *(const uint4*)(kbuf + goff);
      uint4 vv = *(const uint4*)(vbuf + goff);
      unpack8f(kv, &Ks[r][c8 * 8]);
      unpack8f(vv, &Vs[r][c8 * 8]);
    }
    __syncthreads();
    int d = tid & 63, kb = (tid >> 6) * 16;   // kb wave-uniform -> broadcast reads
    float acc[16] = {};
    for (int r = 0; r < CROWS; r++) {
      float vd = Vs[r][d];
      const float4* Kr = (const float4*)(&Ks[r][kb]);
      float4 k0 = Kr[0], k1 = Kr[1], k2 = Kr[2], k3 = Kr[3];
      acc[0] += vd * k0.x;  acc[1] += vd * k0.y;  acc[2] += vd * k0.z;  acc[3] += vd * k0.w;
      acc[4] += vd * k1.x;  acc[5] += vd * k1.y;  acc[6] += vd * k1.z;  acc[7] += vd * k1.w;
      acc[8] += vd * k2.x;  acc[9] += vd * k2.y;  acc[10] += vd * k2.z; acc[11] += vd * k2.w;
      acc[12] += vd * k3.x; acc[13] += vd * k3.y; acc[14] += vd * k3.z; acc[15] += vd * k3.w;
    }
    float* Gp = G + (((size_t)c * H_ + h) * HD_ + d) * HD_ + kb;
#pragma unroll
    for (int j = 0; j < 16; j++) Gp[j] = 0.5f * acc[j];
    __syncthreads();                        // all G stores issued, LDS reads done
    if (tid == 0) {
      __threadfence();                      // make G visible device-wide
      __hip_atomic_fetch_add(&cnt[h], 1, __ATOMIC_RELEASE, __HIP_MEMORY_SCOPE_AGENT);
    }
  }

  // ---------------- stage Q/K/V for phase C (overlaps other blocks' phase A)
  unsigned short* smem = (unsigned short*)sm_raw;
  unsigned short* Qs  = smem;            // 128x64
  unsigned short* Ksh = smem + 8192;     // 128x64
  unsigned short* Vt  = smem + 16384;    // 64x128 (V transposed)
  unsigned short* Mhi = smem + 24576;    // 64x64
  unsigned short* Mlo = smem + 28672;    // 64x64
  unsigned short* Ps  = smem;            // 128x128 overlays Qs+Ksh exactly
#pragma unroll
  for (int it = 0; it < 4; it++) {
    int gi = it * 256 + tid;
    int r = gi >> 3, g8 = gi & 7;
    int bb = r & 1, tt = c * CCH + (r >> 1);
    size_t go = ((size_t)bb * T_ + tt) * D_ + h * HD_ + g8 * 8;
    int qc = (g8 * 8) ^ ((r & 7) << 3);
    *(uint4*)(Qs + r * 64 + qc) = *(const uint4*)(qbuf + go);
    *(uint4*)(Ksh + r * 64 + qc) = *(const uint4*)(kbuf + go);
    uint4 vv = *(const uint4*)(vbuf + go);
    const unsigned short* vp = (const unsigned short*)&vv;
#pragma unroll
    for (int j = 0; j < 8; j++) {
      int d = g8 * 8 + j;
      int t = (d & 7) ^ (d >> 3);
      Vt[d * 128 + (r ^ (t << 3))] = vp[j];
    }
  }

  // ---------------- wait for all chunks of this head ------------------------
  if (tid == 0) {
    while (__hip_atomic_load(&cnt[h], __ATOMIC_ACQUIRE, __HIP_MEMORY_SCOPE_AGENT) < NC) {}
    __threadfence();
  }
  __syncthreads();

  // ---------------- exclusive prefix: Mem = sum_{c'<c} G[c'] (L2-hot) -------
  float macc[16] = {};
  for (int cp = 0; cp < c; cp++) {
    const float4* gp = (const float4*)(G + ((size_t)cp * H_ + h) * (HD_ * HD_)) + tid * 4;
#pragma unroll
    for (int j4 = 0; j4 < 4; j4++) {
      float4 gv = gp[j4];
      macc[j4 * 4]     += gv.x;
      macc[j4 * 4 + 1] += gv.y;
      macc[j4 * 4 + 2] += gv.z;
      macc[j4 * 4 + 3] += gv.w;
    }
  }
#pragma unroll
  for (int j = 0; j < 16; j++) {          // hi/lo bf16 split of Mem into LDS
    int i = tid * 16 + j;
    int d = i >> 6, k = i & 63;
    unsigned short hi = f2b(macc[j]);
    float lo = macc[j] - b2f(hi);
    int col = k ^ ((d & 7) << 3);
    Mhi[d * 64 + col] = hi;
    Mlo[d * 64 + col] = f2b(lo);
  }
  __syncthreads();

  // ---------------- phase C: QK^T, Q@Mem^T, mask, PV ------------------------
  int row0 = w * 32;
  f32x4 sacc[2][8] = {};
  f32x4 yacc[2][4] = {};
#pragma unroll
  for (int kk = 0; kk < 2; kk++) {
    bf16x8 aq[2];
#pragma unroll
    for (int mt = 0; mt < 2; mt++) {
      int row = row0 + mt * 16 + (lane & 15);
      aq[mt] = *(const bf16x8*)(Qs + row * 64 +
                ((kk * 32 + ((lane >> 4) << 3)) ^ ((row & 7) << 3)));
    }
#pragma unroll
    for (int nt = 0; nt < 8; nt++) {
      int row = nt * 16 + (lane & 15);
      bf16x8 bk = *(const bf16x8*)(Ksh + row * 64 +
                ((kk * 32 + ((lane >> 4) << 3)) ^ ((row & 7) << 3)));
#pragma unroll
      for (int mt = 0; mt < 2; mt++)
        sacc[mt][nt] = __builtin_amdgcn_mfma_f32_16x16x32_bf16(aq[mt], bk,
                                                               sacc[mt][nt], 0, 0, 0);
    }
#pragma unroll
    for (int nt = 0; nt < 4; nt++) {
      int row = nt * 16 + (lane & 15);
      int off = row * 64 + ((kk * 32 + ((lane >> 4) << 3)) ^ ((row & 7) << 3));
      bf16x8 bh = *(const bf16x8*)(Mhi + off);
      bf16x8 bl = *(const bf16x8*)(Mlo + off);
#pragma unroll
      for (int mt = 0; mt < 2; mt++) {
        yacc[mt][nt] = __builtin_amdgcn_mfma_f32_16x16x32_bf16(aq[mt], bh,
                                                               yacc[mt][nt], 0, 0, 0);
        yacc[mt][nt] = __builtin_amdgcn_mfma_f32_16x16x32_bf16(aq[mt], bl,
                                                               yacc[mt][nt], 0, 0, 0);
      }
    }
  }
  __syncthreads();

#pragma unroll
  for (int mt = 0; mt < 2; mt++)
#pragma unroll
    for (int nt = 0; nt < 8; nt++)
#pragma unroll
      for (int j = 0; j < 4; j++) {
        int qr = row0 + mt * 16 + ((lane >> 4) << 2) + j;
        int ks = nt * 16 + (lane & 15);
        float v = ((ks >> 1) <= (qr >> 1)) ? sacc[mt][nt][j] * 0.5f : 0.f;
        Ps[qr * 128 + (ks ^ ((qr & 7) << 3))] = f2b(v);
      }
  __syncthreads();

  for (int kb = 0; kb <= w; kb++) {
    bf16x8 ap[2];
#pragma unroll
    for (int mt = 0; mt < 2; mt++) {
      int row = row0 + mt * 16 + (lane & 15);
      ap[mt] = *(const bf16x8*)(Ps + row * 128 +
                ((kb * 32 + ((lane >> 4) << 3)) ^ ((row & 7) << 3)));
    }
#pragma unroll
    for (int nt = 0; nt < 4; nt++) {
      int d = nt * 16 + (lane & 15);
      int t = (d & 7) ^ (d >> 3);
      int gb = (kb * 32 + ((lane >> 4) << 3)) ^ (t << 3);
      bf16x8 bv = *(const bf16x8*)(Vt + d * 128 + gb);
#pragma unroll
      for (int mt = 0; mt < 2; mt++)
        yacc[mt][nt] = __builtin_amdgcn_mfma_f32_16x16x32_bf16(ap[mt], bv,
                                                               yacc[mt][nt], 0, 0, 0);
    }
  }

#pragma unroll
  for (int mt = 0; mt < 2; mt++)
#pragma unroll
    for (int nt = 0; nt < 4; nt++)
#pragma unroll
      for (int j = 0; j < 4; j++) {
        int qr = row0 + mt * 16 + ((lane >> 4) << 2) + j;
        int d = nt * 16 + (lane & 15);
        int bb = qr & 1, tl = qr >> 1;
        ybuf[((size_t)bb * T_ + c * CCH + tl) * D_ + h * HD_ + d] =
            f2b(yacc[mt][nt][j]);
      }
}

extern "C" void kernel_launch(void* const* d_in, const int* in_sizes, int n_in,
                              void* d_out, int out_size, void* d_ws, size_t ws_size,
                              hipStream_t stream) {
  (void)in_sizes; (void)n_in; (void)out_size; (void)ws_size;
  const float* emb  = (const float*)d_in[0];
  const float* pos  = (const float*)d_in[1];
  const float* ln1g = (const float*)d_in[2];
  const float* ln1b = (const float*)d_in[3];
  const float* Wq   = (const float*)d_in[4];
  const float* Wk   = (const float*)d_in[5];
  const float* Wv   = (const float*)d_in[6];
  const float* Wo   = (const float*)d_in[7];
  const float* ln2g = (const float*)d_in[8];
  const float* ln2b = (const float*)d_in[9];
  const float* W1   = (const float*)d_in[10];
  const float* b1   = (const float*)d_in[11];
  const float* W2   = (const float*)d_in[12];
  const float* b2   = (const float*)d_in[13];
  const float* lnfg = (const float*)d_in[14];
  const float* lnfb = (const float*)d_in[15];
  const int*   ids  = (const int*)d_in[16];

  char* w = (char*)d_ws;
  size_t off = 0;
  auto alloc = [&](size_t bytes) -> void* {
    void* p = w + off; off += (bytes + 255) & ~(size_t)255; return p;
  };
  const size_t DD = (size_t)D_ * D_;
  unsigned short* WqkvT = (unsigned short*)alloc(12ull * DD * 2);
  unsigned short* WoT   = (unsigned short*)alloc(4ull * DD * 2);
  unsigned short* W1T   = (unsigned short*)alloc((size_t)L_ * NL_ * HID_ * D_ * 2);
  unsigned short* W2cat = (unsigned short*)alloc((size_t)L_ * D_ * NL_ * HID_ * 2);
  unsigned short* embB  = (unsigned short*)alloc((size_t)V_ * D_ * 2);
  float* bsum           = (float*)alloc((size_t)L_ * D_ * 4);
  int*   cnt            = (int*)alloc((size_t)L_ * H_ * 4);
  float* x              = (float*)alloc((size_t)NROW * D_ * 4);
  unsigned short* h     = (unsigned short*)alloc((size_t)NROW * D_ * 2);
  // qkv+ybuf+G+pad = 24 MB contiguous; dead during CMS -> split-K partials overlay
  unsigned short* qkv   = (unsigned short*)alloc(3ull * NROW * D_ * 2);   // 12 MB
  unsigned short* ybuf  = (unsigned short*)alloc((size_t)NROW * D_ * 2);  //  4 MB
  float* G              = (float*)alloc((size_t)NC * H_ * HD_ * HD_ * 4); //  4 MB
  (void)alloc((size_t)NC * H_ * HD_ * HD_ * 4);                           //  4 MB pad
  float* parts          = (float*)qkv;
  unsigned short* hmid  = (unsigned short*)alloc((size_t)NROW * NL_ * HID_ * 2);

  dim3 blk(256);
  k_prep<<<dim3(46729), blk, 0, stream>>>(emb, pos, ids, Wq, Wk, Wv, Wo, W1, W2, b2,
                                          ln1g, ln1b,
                                          WqkvT, WoT, W1T, W2cat, embB, bsum, x, h,
                                          cnt);

  unsigned short* qb = qkv;
  unsigned short* kb = qkv + (size_t)NROW * D_;
  unsigned short* vb = qkv + 2ull * NROW * D_;

  for (int l = 0; l < L_; l++) {
    // h holds LN1(x) (from prep for l=0, from k_cmsred_ln otherwise)
    k_gemm128<E_QKV><<<dim3(12, 32), blk, 0, stream>>>(
        h, WqkvT + (size_t)l * 3 * DD, bsum, qkv, D_, D_, 3 * D_, D_);
    k_attn<<<dim3(NC, H_), blk, 0, stream>>>(qb, kb, vb, G, cnt + l * H_, ybuf);
    k_gemm128<E_RES><<<dim3(4, 32), blk, 0, stream>>>(
        ybuf, WoT + (size_t)l * DD, x, x, D_, D_, D_, D_);
    k_ln<<<dim3(NROW), dim3(128), 0, stream>>>(x, ln2g + l * D_, ln2b + l * D_, h);
    k_gemm256<E_GELU><<<dim3(24, 16), dim3(512), 0, stream>>>(
        h, W1T + (size_t)l * NL_ * HID_ * D_, b1 + (size_t)l * NL_ * HID_, hmid,
        D_, NL_ * HID_, NL_ * HID_);
    k_gemm128<E_PART><<<dim3(4, 32, 3), blk, 0, stream>>>(
        hmid, W2cat + (size_t)l * D_ * NL_ * HID_, bsum, parts,
        2048, NL_ * HID_, D_, D_);
    const float* gn = (l < 3) ? (ln1g + (l + 1) * D_) : lnfg;
    const float* bn = (l < 3) ? (ln1b + (l + 1) * D_) : lnfb;
    k_cmsred_ln<<<dim3(NROW / 2), blk, 0, stream>>>(x, parts, bsum + l * D_, gn, bn, h);
  }
  k_gemm256<E_F32><<<dim3(125, 16), dim3(512), 0, stream>>>(
      h, embB, bsum, d_out, D_, V_, V_);
}

// Round 10
// 966.945 us; speedup vs baseline: 1.1735x; 1.1735x over previous
//
#include <hip/hip_runtime.h>
#include <stdint.h>

// ---- problem constants ----
#define B_ 2
#define T_ 2048
#define D_ 512
#define H_ 8
#define HD_ 64
#define V_ 32000
#define L_ 4
#define NL_ 3
#define HID_ 2048
#define NROW 4096          // B*T
#define CCH 64             // chunk timesteps
#define CROWS 128          // rows per chunk (CCH*B)
#define NC 32              // T/CCH
#define EPS_ 1e-5f

typedef __attribute__((ext_vector_type(8))) __bf16 bf16x8;
typedef __attribute__((ext_vector_type(4))) float f32x4;

__device__ __forceinline__ float b2f(unsigned short u) {
  union { uint32_t i; float f; } v; v.i = ((uint32_t)u) << 16; return v.f;
}
__device__ __forceinline__ unsigned short f2b(float f) {
  union { float f; uint32_t i; } v; v.f = f;
  uint32_t u = v.i;
  u += 0x7fffu + ((u >> 16) & 1u);   // RNE
  return (unsigned short)(u >> 16);
}

// ================= mega-prep: weights + embed + layer-0 LN1 in ONE dispatch ==
__global__ __launch_bounds__(256) void k_prep(
    const float* __restrict__ emb, const float* __restrict__ pos,
    const int* __restrict__ ids,
    const float* __restrict__ Wq, const float* __restrict__ Wk,
    const float* __restrict__ Wv, const float* __restrict__ Wo,
    const float* __restrict__ W1, const float* __restrict__ W2,
    const float* __restrict__ b2,
    const float* __restrict__ ln1g, const float* __restrict__ ln1b,
    unsigned short* __restrict__ WqkvT, unsigned short* __restrict__ WoT,
    unsigned short* __restrict__ W1T, unsigned short* __restrict__ W2cat,
    unsigned short* __restrict__ embB, float* __restrict__ bsum,
    float* __restrict__ x, unsigned short* __restrict__ h) {
  int bid = blockIdx.x, tid = threadIdx.x;
  __shared__ float tile[32][33];
  __shared__ float red[4], red2[4];
  int tx = tid & 31, ty = tid >> 5;
  if (bid < 4096) {                       // Wq/Wk/Wv (z=l*3+m) + Wo transpose
    int z = bid >> 8, r = bid & 255;
    int bx = (r & 15) * 32, by = (r >> 4) * 32;
    const float* in; unsigned short* out;
    if (z < 12) {
      int l = z / 3, m = z - l * 3;
      in = (m == 0 ? Wq : m == 1 ? Wk : Wv) + (size_t)l * D_ * D_;
      out = WqkvT + (size_t)z * D_ * D_;
    } else {
      in = Wo + (size_t)(z - 12) * D_ * D_;
      out = WoT + (size_t)(z - 12) * D_ * D_;
    }
#pragma unroll
    for (int i = 0; i < 4; i++)
      tile[ty + 8 * i][tx] = in[(size_t)(by + ty + 8 * i) * D_ + bx + tx];
    __syncthreads();
#pragma unroll
    for (int i = 0; i < 4; i++)
      out[(size_t)(bx + ty + 8 * i) * D_ + by + tx] = f2b(tile[tx][ty + 8 * i]);
  } else if (bid < 16384) {               // W1 [z][512][2048] -> W1T [z][2048][512]
    int s = bid - 4096;
    int z = s >> 10, r = s & 1023;
    int bx = (r & 63) * 32, by = (r >> 6) * 32;
    const float* in = W1 + (size_t)z * D_ * HID_;
    unsigned short* out = W1T + (size_t)z * HID_ * D_;
#pragma unroll
    for (int i = 0; i < 4; i++)
      tile[ty + 8 * i][tx] = in[(size_t)(by + ty + 8 * i) * HID_ + bx + tx];
    __syncthreads();
#pragma unroll
    for (int i = 0; i < 4; i++)
      out[(size_t)(bx + ty + 8 * i) * D_ + by + tx] = f2b(tile[tx][ty + 8 * i]);
  } else if (bid < 28672) {               // W2 [z][2048][512] -> W2cat[l][d][n*2048+k]
    int s = bid - 16384;
    int z = s >> 10, r = s & 1023;
    int l = z / 3, n = z - l * 3;
    int bx = (r & 15) * 32, by = (r >> 4) * 32;   // bx: d, by: k
    const float* in = W2 + (size_t)z * HID_ * D_;
#pragma unroll
    for (int i = 0; i < 4; i++)
      tile[ty + 8 * i][tx] = in[(size_t)(by + ty + 8 * i) * D_ + bx + tx];
    __syncthreads();
#pragma unroll
    for (int i = 0; i < 4; i++)
      W2cat[((size_t)l * D_ + bx + ty + 8 * i) * (NL_ * HID_) + n * HID_ + by + tx] =
          f2b(tile[tx][ty + 8 * i]);
  } else if (bid < 44672) {               // emb f32 -> bf16
    int s = bid - 28672;
    int base = (s * 256 + tid) * 4;
    float4 v = *(const float4*)(emb + base);
    unsigned short o[4] = { f2b(v.x), f2b(v.y), f2b(v.z), f2b(v.w) };
    *(uint2*)(embB + base) = *(const uint2*)o;
  } else if (bid < 46720) {               // embed + LN1(layer0): 2 rows per block
    int s = bid - 44672;
    int i = s * 256 + tid;
    int row = i >> 7, cg = i & 127;
    int t = row & (T_ - 1);
    int id = ids[row];
    float4 e = ((const float4*)(emb + (size_t)id * D_))[cg];
    float4 p = ((const float4*)(pos + (size_t)t * D_))[cg];
    float4 xv; xv.x = e.x + p.x; xv.y = e.y + p.y; xv.z = e.z + p.z; xv.w = e.w + p.w;
    ((float4*)(x + (size_t)row * D_))[cg] = xv;
    float sum = xv.x + xv.y + xv.z + xv.w;
#pragma unroll
    for (int o = 32; o >= 1; o >>= 1) sum += __shfl_xor(sum, o);
    int wv = tid >> 6;
    if ((tid & 63) == 0) red[wv] = sum;
    __syncthreads();
    int wb = (tid >> 7) * 2;
    float mu = (red[wb] + red[wb + 1]) * (1.f / D_);
    float dx = xv.x - mu, dy = xv.y - mu, dz = xv.z - mu, dw = xv.w - mu;
    float s2 = dx * dx + dy * dy + dz * dz + dw * dw;
#pragma unroll
    for (int o = 32; o >= 1; o >>= 1) s2 += __shfl_xor(s2, o);
    if ((tid & 63) == 0) red2[wv] = s2;
    __syncthreads();
    float var = (red2[wb] + red2[wb + 1]) * (1.f / D_);
    float rs = rsqrtf(var + EPS_);
    float4 gv = ((const float4*)ln1g)[cg];
    float4 bv = ((const float4*)ln1b)[cg];
    unsigned short o4[4] = { f2b(dx * rs * gv.x + bv.x), f2b(dy * rs * gv.y + bv.y),
                             f2b(dz * rs * gv.z + bv.z), f2b(dw * rs * gv.w + bv.w) };
    *(uint2*)(h + (size_t)row * D_ + cg * 4) = *(const uint2*)o4;
  } else {                                // bsum
    int s = bid - 46720;
    int l = s >> 1, d = (s & 1) * 256 + tid;
    float acc = 0.f;
#pragma unroll
    for (int n = 0; n < NL_; n++) acc += b2[((size_t)l * NL_ + n) * D_ + d];
    bsum[(size_t)l * D_ + d] = acc;
  }
}

// ---- layernorm (LN2): f32 row -> bf16 row ----
__global__ __launch_bounds__(128) void k_ln(
    const float* __restrict__ x, const float* __restrict__ g,
    const float* __restrict__ b, unsigned short* __restrict__ out) {
  int row = blockIdx.x;
  int tid = threadIdx.x;
  const float* xr = x + (size_t)row * D_;
  float4 v = ((const float4*)xr)[tid];
  float s = v.x + v.y + v.z + v.w;
#pragma unroll
  for (int o = 32; o >= 1; o >>= 1) s += __shfl_xor(s, o);
  __shared__ float red[2], red2[2];
  int wv = tid >> 6;
  if ((tid & 63) == 0) red[wv] = s;
  __syncthreads();
  float mu = (red[0] + red[1]) * (1.f / D_);
  float dx = v.x - mu, dy = v.y - mu, dz = v.z - mu, dw = v.w - mu;
  float s2 = dx * dx + dy * dy + dz * dz + dw * dw;
#pragma unroll
  for (int o = 32; o >= 1; o >>= 1) s2 += __shfl_xor(s2, o);
  if ((tid & 63) == 0) red2[wv] = s2;
  __syncthreads();
  float var = (red2[0] + red2[1]) * (1.f / D_);
  float rs = rsqrtf(var + EPS_);
  float4 gv = ((const float4*)g)[tid];
  float4 bv = ((const float4*)b)[tid];
  unsigned short o4[4] = { f2b(dx * rs * gv.x + bv.x), f2b(dy * rs * gv.y + bv.y),
                           f2b(dz * rs * gv.z + bv.z), f2b(dw * rs * gv.w + bv.w) };
  *(uint2*)(out + (size_t)row * D_ + tid * 4) = *(const uint2*)o4;
}

// ---- cms reduce + next LN fused ----
__global__ __launch_bounds__(256) void k_cmsred_ln(
    float* __restrict__ x, const float* __restrict__ parts,
    const float* __restrict__ bsum, const float* __restrict__ g,
    const float* __restrict__ b, unsigned short* __restrict__ h) {
  int bid = blockIdx.x, tid = threadIdx.x;
  int row = bid * 2 + (tid >> 7);
  int cg = tid & 127;
  size_t base = (size_t)row * D_ + cg * 4;
  float4 xv = *(const float4*)(x + base);
  float4 p0 = *(const float4*)(parts + base);
  float4 p1 = *(const float4*)(parts + (size_t)NROW * D_ + base);
  float4 p2 = *(const float4*)(parts + 2ull * NROW * D_ + base);
  float4 bs = *(const float4*)(bsum + cg * 4);
  const float k3 = 1.f / 3.f;
  xv.x += (p0.x + p1.x + p2.x + bs.x) * k3;
  xv.y += (p0.y + p1.y + p2.y + bs.y) * k3;
  xv.z += (p0.z + p1.z + p2.z + bs.z) * k3;
  xv.w += (p0.w + p1.w + p2.w + bs.w) * k3;
  *(float4*)(x + base) = xv;
  float sum = xv.x + xv.y + xv.z + xv.w;
#pragma unroll
  for (int o = 32; o >= 1; o >>= 1) sum += __shfl_xor(sum, o);
  __shared__ float red[4], red2[4];
  int wv = tid >> 6;
  if ((tid & 63) == 0) red[wv] = sum;
  __syncthreads();
  int wb = (tid >> 7) * 2;
  float mu = (red[wb] + red[wb + 1]) * (1.f / D_);
  float dx = xv.x - mu, dy = xv.y - mu, dz = xv.z - mu, dw = xv.w - mu;
  float s2 = dx * dx + dy * dy + dz * dz + dw * dw;
#pragma unroll
  for (int o = 32; o >= 1; o >>= 1) s2 += __shfl_xor(s2, o);
  if ((tid & 63) == 0) red2[wv] = s2;
  __syncthreads();
  float var = (red2[wb] + red2[wb + 1]) * (1.f / D_);
  float rs = rsqrtf(var + EPS_);
  float4 gv = ((const float4*)g)[cg];
  float4 bv = ((const float4*)b)[cg];
  unsigned short o4[4] = { f2b(dx * rs * gv.x + bv.x), f2b(dy * rs * gv.y + bv.y),
                           f2b(dz * rs * gv.z + bv.z), f2b(dw * rs * gv.w + bv.w) };
  *(uint2*)(h + base) = *(const uint2*)o4;
}

// ================= GEMM templates =================
enum { E_QKV = 0, E_RES = 1, E_GELU = 2, E_PART = 3, E_F32 = 4 };

// stage a TRx64 bf16 tile, source-side XOR swizzle, gload_lds w16
template <int TR, int NW>
__device__ __forceinline__ void stage_tile(
    const unsigned short* __restrict__ gbase, int ldk, unsigned short* lds,
    int wave, int lane) {
#pragma unroll
  for (int q = 0; q < 4; q++) {
    int Lb = (q * NW + wave) << 10;             // wave-uniform LDS byte base
    int L = Lb + lane * 16;
    int row = L >> 7;
    int colb = (L & 127) ^ ((row & 7) << 4);    // involutive swizzle
    const unsigned short* gsrc = gbase + (size_t)row * ldk + (colb >> 1);
    __builtin_amdgcn_global_load_lds(
        (const __attribute__((address_space(1))) uint32_t*)gsrc,
        (__attribute__((address_space(3))) uint32_t*)(lds + (Lb >> 1)),
        16, 0, 0);
  }
}

// ---- 128x128 tile, 2-phase prologue-prefetch double-buffer ----
template <int EPI>
__global__ __launch_bounds__(256, 2) void k_gemm128(
    const unsigned short* __restrict__ A,   // [M][ldk] bf16
    const unsigned short* __restrict__ Bt,  // [N][ldk] bf16
    const float* __restrict__ bias,
    void* __restrict__ Out,
    int Kext, int ldk, int N, int ldOut) {
  int z = blockIdx.z;
  A  += (size_t)z * Kext;                  // split-K column offset
  Bt += (size_t)z * Kext;
  int lane = threadIdx.x & 63, wave = threadIdx.x >> 6;
  int wm = wave >> 1, wn = wave & 1;
  int bx = blockIdx.x, by = blockIdx.y;

  __shared__ __align__(16) unsigned short As[2][128 * 64];
  __shared__ __align__(16) unsigned short Bs[2][128 * 64];

  const unsigned short* Ab = A + (size_t)by * 128 * ldk;
  const unsigned short* Bb = Bt + (size_t)bx * 128 * ldk;

  f32x4 acc[4][4] = {};
  int nk = Kext / 64;
  stage_tile<128, 4>(Ab, ldk, As[0], wave, lane);
  stage_tile<128, 4>(Bb, ldk, Bs[0], wave, lane);
  __syncthreads();
  for (int kt = 0; kt < nk; kt++) {
    int cur = kt & 1;
    if (kt + 1 < nk) {                     // issue next tile BEFORE compute
      stage_tile<128, 4>(Ab + (size_t)(kt + 1) * 64, ldk, As[cur ^ 1], wave, lane);
      stage_tile<128, 4>(Bb + (size_t)(kt + 1) * 64, ldk, Bs[cur ^ 1], wave, lane);
    }
    const char* Ac = (const char*)As[cur];
    const char* Bc = (const char*)Bs[cur];
#pragma unroll
    for (int kk = 0; kk < 2; kk++) {
      bf16x8 af[4], bfr[4];
#pragma unroll
      for (int mt = 0; mt < 4; mt++) {
        int row = wm * 64 + mt * 16 + (lane & 15);
        int off = ((row << 7) | (kk * 64 + ((lane >> 4) << 4))) ^ ((row & 7) << 4);
        af[mt] = *(const bf16x8*)(Ac + off);
      }
#pragma unroll
      for (int nt = 0; nt < 4; nt++) {
        int row = wn * 64 + nt * 16 + (lane & 15);
        int off = ((row << 7) | (kk * 64 + ((lane >> 4) << 4))) ^ ((row & 7) << 4);
        bfr[nt] = *(const bf16x8*)(Bc + off);
      }
#pragma unroll
      for (int mt = 0; mt < 4; mt++)
#pragma unroll
        for (int nt = 0; nt < 4; nt++)
          acc[mt][nt] = __builtin_amdgcn_mfma_f32_16x16x32_bf16(
              af[mt], bfr[nt], acc[mt][nt], 0, 0, 0);
    }
    __syncthreads();   // drains vmcnt: next tile landed while we computed
  }

  int gm = by * 128 + wm * 64;
  int gn = bx * 128 + wn * 64;
#pragma unroll
  for (int mt = 0; mt < 4; mt++) {
#pragma unroll
    for (int nt = 0; nt < 4; nt++) {
      int m0 = gm + mt * 16 + ((lane >> 4) << 2);
      int n = gn + nt * 16 + (lane & 15);
#pragma unroll
      for (int j = 0; j < 4; j++) {
        float v = acc[mt][nt][j];
        int m = m0 + j;
        if constexpr (EPI == E_QKV) {          // N=1536 -> qkv[zq][row][col]
          int zq = n >> 9, col = n & 511;
          ((unsigned short*)Out)[((size_t)zq * NROW + m) * D_ + col] = f2b(v);
        } else if constexpr (EPI == E_RES) {   // x = resid + v
          size_t idx = (size_t)m * ldOut + n;
          ((float*)Out)[idx] = bias[idx] + v;
        } else {                               // E_PART: parts[z][m][n]
          ((float*)Out)[(size_t)z * NROW * D_ + (size_t)m * ldOut + n] = v;
        }
      }
    }
  }
}

// ---- 256x256x64, 8 waves, single-buffer (2 blk/CU co-residency) ----
template <int EPI>
__global__ __launch_bounds__(512) void k_gemm256(
    const unsigned short* __restrict__ A,
    const unsigned short* __restrict__ Bt,
    const float* __restrict__ bias,
    void* __restrict__ Out,
    int K, int N, int ldOut) {
  int lane = threadIdx.x & 63, wave = threadIdx.x >> 6;   // 8 waves
  int wm = wave >> 2, wn = wave & 3;
  int bx = blockIdx.x, by = blockIdx.y;
  if constexpr (EPI == E_F32) {
    // supertile remap: 25 bx x 16 by groups for B-panel L2/L3 reuse (gridDim.x=125)
    int lin = blockIdx.y * 125 + blockIdx.x;
    int seg = lin / 400, rem = lin % 400;
    bx = seg * 25 + rem % 25;  by = rem / 25;
  }

  __shared__ __align__(16) unsigned short As[256 * 64];
  __shared__ __align__(16) unsigned short Bs[256 * 64];

  const unsigned short* Ab = A + (size_t)by * 256 * K;
  const unsigned short* Bb = Bt + (size_t)bx * 256 * K;

  f32x4 acc[8][4] = {};
  int nk = K / 64;
  for (int kt = 0; kt < nk; kt++) {
    stage_tile<256, 8>(Ab + (size_t)kt * 64, K, As, wave, lane);
    stage_tile<256, 8>(Bb + (size_t)kt * 64, K, Bs, wave, lane);
    __syncthreads();
    const char* Ac = (const char*)As;
    const char* Bc = (const char*)Bs;
#pragma unroll
    for (int kk = 0; kk < 2; kk++) {
      bf16x8 af[8], bfr[4];
#pragma unroll
      for (int mt = 0; mt < 8; mt++) {
        int row = wm * 128 + mt * 16 + (lane & 15);
        int off = ((row << 7) | (kk * 64 + ((lane >> 4) << 4))) ^ ((row & 7) << 4);
        af[mt] = *(const bf16x8*)(Ac + off);
      }
#pragma unroll
      for (int nt = 0; nt < 4; nt++) {
        int row = wn * 64 + nt * 16 + (lane & 15);
        int off = ((row << 7) | (kk * 64 + ((lane >> 4) << 4))) ^ ((row & 7) << 4);
        bfr[nt] = *(const bf16x8*)(Bc + off);
      }
#pragma unroll
      for (int mt = 0; mt < 8; mt++)
#pragma unroll
        for (int nt = 0; nt < 4; nt++)
          acc[mt][nt] = __builtin_amdgcn_mfma_f32_16x16x32_bf16(
              af[mt], bfr[nt], acc[mt][nt], 0, 0, 0);
    }
    __syncthreads();
  }

  int gm = by * 256 + wm * 128;
  int gn = bx * 256 + wn * 64;
#pragma unroll
  for (int mt = 0; mt < 8; mt++) {
#pragma unroll
    for (int nt = 0; nt < 4; nt++) {
      int m0 = gm + mt * 16 + ((lane >> 4) << 2);
      int n = gn + nt * 16 + (lane & 15);
#pragma unroll
      for (int j = 0; j < 4; j++) {
        float v = acc[mt][nt][j];
        size_t idx = (size_t)(m0 + j) * ldOut + n;
        if constexpr (EPI == E_GELU) {
          v += bias[n];
          float u2 = 1.5957691216057308f * (v + 0.044715f * v * v * v);
          float sg = 1.f / (1.f + __expf(-u2));   // tanh-approx GELU
          ((unsigned short*)Out)[idx] = f2b(v * sg);
        } else {                                  // E_F32 (head)
          ((float*)Out)[idx] = v;
        }
      }
    }
  }
}

// ---- attention phase A: G[c,h,d,k] = 0.5 * sum_rows v_d * k_k ----
__device__ __forceinline__ void unpack8f(uint4 u, float* dst) {
  dst[0] = b2f((unsigned short)(u.x & 0xffff)); dst[1] = b2f((unsigned short)(u.x >> 16));
  dst[2] = b2f((unsigned short)(u.y & 0xffff)); dst[3] = b2f((unsigned short)(u.y >> 16));
  dst[4] = b2f((unsigned short)(u.z & 0xffff)); dst[5] = b2f((unsigned short)(u.z >> 16));
  dst[6] = b2f((unsigned short)(u.w & 0xffff)); dst[7] = b2f((unsigned short)(u.w >> 16));
}

__global__ __launch_bounds__(256) void k_attnA(
    const unsigned short* __restrict__ kbuf, const unsigned short* __restrict__ vbuf,
    float* __restrict__ G) {
  int c = blockIdx.x, h = blockIdx.y;
  __shared__ __align__(16) float Ks[CROWS][HD_];
  __shared__ __align__(16) float Vs[CROWS][HD_];
  int tid = threadIdx.x;
#pragma unroll
  for (int it = 0; it < 4; it++) {
    int gi = it * 256 + tid;
    int r = gi >> 3, c8 = gi & 7;
    int bb = r & 1, tt = c * CCH + (r >> 1);
    size_t goff = ((size_t)bb * T_ + tt) * D_ + h * HD_ + c8 * 8;
    uint4 kv = *(const uint4*)(kbuf + goff);
    uint4 vv = *(const uint4*)(vbuf + goff);
    unpack8f(kv, &Ks[r][c8 * 8]);
    unpack8f(vv, &Vs[r][c8 * 8]);
  }
  __syncthreads();
  int d = tid & 63, kb = (tid >> 6) * 16;     // kb wave-uniform -> broadcast reads
  float acc[16] = {};
  for (int r = 0; r < CROWS; r++) {
    float vd = Vs[r][d];
    const float4* Kr = (const float4*)(&Ks[r][kb]);     // 4x ds_read_b128 broadcast
    float4 k0 = Kr[0], k1 = Kr[1], k2 = Kr[2], k3 = Kr[3];
    acc[0] += vd * k0.x;  acc[1] += vd * k0.y;  acc[2] += vd * k0.z;  acc[3] += vd * k0.w;
    acc[4] += vd * k1.x;  acc[5] += vd * k1.y;  acc[6] += vd * k1.z;  acc[7] += vd * k1.w;
    acc[8] += vd * k2.x;  acc[9] += vd * k2.y;  acc[10] += vd * k2.z; acc[11] += vd * k2.w;
    acc[12] += vd * k3.x; acc[13] += vd * k3.y; acc[14] += vd * k3.z; acc[15] += vd * k3.w;
  }
  float* Gp = G + (((size_t)c * H_ + h) * HD_ + d) * HD_ + kb;
#pragma unroll
  for (int j = 0; j < 16; j++) Gp[j] = 0.5f * acc[j];
}

// ---- attention phase B: register-resident exclusive prefix ----
__global__ __launch_bounds__(256) void k_attnB(const float* __restrict__ G,
                                               float* __restrict__ Mem) {
  int hh = blockIdx.x >> 4, seg = blockIdx.x & 15;
  int idx = seg * 256 + threadIdx.x;
  float g[NC];
#pragma unroll
  for (int c = 0; c < NC; c++)
    g[c] = G[((size_t)c * H_ + hh) * (HD_ * HD_) + idx];
  float m = 0.f;
#pragma unroll
  for (int c = 0; c < NC; c++) {
    Mem[((size_t)c * H_ + hh) * (HD_ * HD_) + idx] = m;
    m += g[c];
  }
}

// ---- attention phase C (MFMA): Y = Q@Mem^T (hi/lo bf16) + causal(QK^T*0.5)@V ----
__global__ __launch_bounds__(256) void k_attnC(
    const unsigned short* __restrict__ qbuf, const unsigned short* __restrict__ kbuf,
    const unsigned short* __restrict__ vbuf, const float* __restrict__ Mem,
    unsigned short* __restrict__ ybuf) {
  int c = blockIdx.x, h = blockIdx.y;
  __shared__ __align__(16) unsigned short smem[32768];   // 64 KB, all XOR-swizzled
  unsigned short* Qs  = smem;            // 128x64
  unsigned short* Ksh = smem + 8192;     // 128x64
  unsigned short* Vt  = smem + 16384;    // 64x128 (V transposed)
  unsigned short* Mhi = smem + 24576;    // 64x64
  unsigned short* Mlo = smem + 28672;    // 64x64
  unsigned short* Ps  = smem;            // 128x128 overlays Qs+Ksh exactly

  int tid = threadIdx.x, lane = tid & 63, w = tid >> 6;
#pragma unroll
  for (int it = 0; it < 4; it++) {
    int gi = it * 256 + tid;
    int r = gi >> 3, g8 = gi & 7;
    int bb = r & 1, tt = c * CCH + (r >> 1);
    size_t go = ((size_t)bb * T_ + tt) * D_ + h * HD_ + g8 * 8;
    int qc = (g8 * 8) ^ ((r & 7) << 3);
    *(uint4*)(Qs + r * 64 + qc) = *(const uint4*)(qbuf + go);
    *(uint4*)(Ksh + r * 64 + qc) = *(const uint4*)(kbuf + go);
    uint4 vv = *(const uint4*)(vbuf + go);
    const unsigned short* vp = (const unsigned short*)&vv;
#pragma unroll
    for (int j = 0; j < 8; j++) {
      int d = g8 * 8 + j;
      int t = (d & 7) ^ (d >> 3);
      Vt[d * 128 + (r ^ (t << 3))] = vp[j];
    }
  }
  {
    const float* Mp = Mem + (((size_t)c * H_ + h) << 12);
#pragma unroll
    for (int it = 0; it < 16; it++) {
      int i = it * 256 + tid;
      int d = i >> 6, k = i & 63;
      float m = Mp[i];
      unsigned short hi = f2b(m);
      float lo = m - b2f(hi);
      int col = k ^ ((d & 7) << 3);
      Mhi[d * 64 + col] = hi;
      Mlo[d * 64 + col] = f2b(lo);
    }
  }
  __syncthreads();

  int row0 = w * 32;
  f32x4 sacc[2][8] = {};
  f32x4 yacc[2][4] = {};
#pragma unroll
  for (int kk = 0; kk < 2; kk++) {
    bf16x8 aq[2];
#pragma unroll
    for (int mt = 0; mt < 2; mt++) {
      int row = row0 + mt * 16 + (lane & 15);
      aq[mt] = *(const bf16x8*)(Qs + row * 64 +
                ((kk * 32 + ((lane >> 4) << 3)) ^ ((row & 7) << 3)));
    }
#pragma unroll
    for (int nt = 0; nt < 8; nt++) {
      int row = nt * 16 + (lane & 15);
      bf16x8 bk = *(const bf16x8*)(Ksh + row * 64 +
                ((kk * 32 + ((lane >> 4) << 3)) ^ ((row & 7) << 3)));
#pragma unroll
      for (int mt = 0; mt < 2; mt++)
        sacc[mt][nt] = __builtin_amdgcn_mfma_f32_16x16x32_bf16(aq[mt], bk,
                                                               sacc[mt][nt], 0, 0, 0);
    }
#pragma unroll
    for (int nt = 0; nt < 4; nt++) {
      int row = nt * 16 + (lane & 15);
      int off = row * 64 + ((kk * 32 + ((lane >> 4) << 3)) ^ ((row & 7) << 3));
      bf16x8 bh = *(const bf16x8*)(Mhi + off);
      bf16x8 bl = *(const bf16x8*)(Mlo + off);
#pragma unroll
      for (int mt = 0; mt < 2; mt++) {
        yacc[mt][nt] = __builtin_amdgcn_mfma_f32_16x16x32_bf16(aq[mt], bh,
                                                               yacc[mt][nt], 0, 0, 0);
        yacc[mt][nt] = __builtin_amdgcn_mfma_f32_16x16x32_bf16(aq[mt], bl,
                                                               yacc[mt][nt], 0, 0, 0);
      }
    }
  }
  __syncthreads();

#pragma unroll
  for (int mt = 0; mt < 2; mt++)
#pragma unroll
    for (int nt = 0; nt < 8; nt++)
#pragma unroll
      for (int j = 0; j < 4; j++) {
        int qr = row0 + mt * 16 + ((lane >> 4) << 2) + j;
        int ks = nt * 16 + (lane & 15);
        float v = ((ks >> 1) <= (qr >> 1)) ? sacc[mt][nt][j] * 0.5f : 0.f;
        Ps[qr * 128 + (ks ^ ((qr & 7) << 3))] = f2b(v);
      }
  __syncthreads();

  for (int kb = 0; kb <= w; kb++) {
    bf16x8 ap[2];
#pragma unroll
    for (int mt = 0; mt < 2; mt++) {
      int row = row0 + mt * 16 + (lane & 15);
      ap[mt] = *(const bf16x8*)(Ps + row * 128 +
                ((kb * 32 + ((lane >> 4) << 3)) ^ ((row & 7) << 3)));
    }
#pragma unroll
    for (int nt = 0; nt < 4; nt++) {
      int d = nt * 16 + (lane & 15);
      int t = (d & 7) ^ (d >> 3);
      int gb = (kb * 32 + ((lane >> 4) << 3)) ^ (t << 3);
      bf16x8 bv = *(const bf16x8*)(Vt + d * 128 + gb);
#pragma unroll
      for (int mt = 0; mt < 2; mt++)
        yacc[mt][nt] = __builtin_amdgcn_mfma_f32_16x16x32_bf16(ap[mt], bv,
                                                               yacc[mt][nt], 0, 0, 0);
    }
  }

#pragma unroll
  for (int mt = 0; mt < 2; mt++)
#pragma unroll
    for (int nt = 0; nt < 4; nt++)
#pragma unroll
      for (int j = 0; j < 4; j++) {
        int qr = row0 + mt * 16 + ((lane >> 4) << 2) + j;
        int d = nt * 16 + (lane & 15);
        int bb = qr & 1, tl = qr >> 1;
        ybuf[((size_t)bb * T_ + c * CCH + tl) * D_ + h * HD_ + d] =
            f2b(yacc[mt][nt][j]);
      }
}

extern "C" void kernel_launch(void* const* d_in, const int* in_sizes, int n_in,
                              void* d_out, int out_size, void* d_ws, size_t ws_size,
                              hipStream_t stream) {
  (void)in_sizes; (void)n_in; (void)out_size; (void)ws_size;
  const float* emb  = (const float*)d_in[0];
  const float* pos  = (const float*)d_in[1];
  const float* ln1g = (const float*)d_in[2];
  const float* ln1b = (const float*)d_in[3];
  const float* Wq   = (const float*)d_in[4];
  const float* Wk   = (const float*)d_in[5];
  const float* Wv   = (const float*)d_in[6];
  const float* Wo   = (const float*)d_in[7];
  const float* ln2g = (const float*)d_in[8];
  const float* ln2b = (const float*)d_in[9];
  const float* W1   = (const float*)d_in[10];
  const float* b1   = (const float*)d_in[11];
  const float* W2   = (const float*)d_in[12];
  const float* b2   = (const float*)d_in[13];
  const float* lnfg = (const float*)d_in[14];
  const float* lnfb = (const float*)d_in[15];
  const int*   ids  = (const int*)d_in[16];

  char* w = (char*)d_ws;
  size_t off = 0;
  auto alloc = [&](size_t bytes) -> void* {
    void* p = w + off; off += (bytes + 255) & ~(size_t)255; return p;
  };
  const size_t DD = (size_t)D_ * D_;
  unsigned short* WqkvT = (unsigned short*)alloc(12ull * DD * 2);
  unsigned short* WoT   = (unsigned short*)alloc(4ull * DD * 2);
  unsigned short* W1T   = (unsigned short*)alloc((size_t)L_ * NL_ * HID_ * D_ * 2);
  unsigned short* W2cat = (unsigned short*)alloc((size_t)L_ * D_ * NL_ * HID_ * 2);
  unsigned short* embB  = (unsigned short*)alloc((size_t)V_ * D_ * 2);
  float* bsum           = (float*)alloc((size_t)L_ * D_ * 4);
  float* x              = (float*)alloc((size_t)NROW * D_ * 4);
  unsigned short* h     = (unsigned short*)alloc((size_t)NROW * D_ * 2);
  // qkv+ybuf+G+Mem = 24 MB contiguous; dead during CMS -> split-K partials overlay
  unsigned short* qkv   = (unsigned short*)alloc(3ull * NROW * D_ * 2);   // 12 MB
  unsigned short* ybuf  = (unsigned short*)alloc((size_t)NROW * D_ * 2);  //  4 MB
  float* G              = (float*)alloc((size_t)NC * H_ * HD_ * HD_ * 4); //  4 MB
  float* Mem            = (float*)alloc((size_t)NC * H_ * HD_ * HD_ * 4); //  4 MB
  float* parts          = (float*)qkv;
  unsigned short* hmid  = (unsigned short*)alloc((size_t)NROW * NL_ * HID_ * 2);

  dim3 blk(256);
  k_prep<<<dim3(46728), blk, 0, stream>>>(emb, pos, ids, Wq, Wk, Wv, Wo, W1, W2, b2,
                                          ln1g, ln1b,
                                          WqkvT, WoT, W1T, W2cat, embB, bsum, x, h);

  unsigned short* qb = qkv;
  unsigned short* kb = qkv + (size_t)NROW * D_;
  unsigned short* vb = qkv + 2ull * NROW * D_;

  for (int l = 0; l < L_; l++) {
    // h holds LN1(x) (from prep for l=0, from k_cmsred_ln otherwise)
    k_gemm128<E_QKV><<<dim3(12, 32), blk, 0, stream>>>(
        h, WqkvT + (size_t)l * 3 * DD, bsum, qkv, D_, D_, 3 * D_, D_);
    k_attnA<<<dim3(NC, H_), blk, 0, stream>>>(kb, vb, G);
    k_attnB<<<dim3(H_ * 16), blk, 0, stream>>>(G, Mem);
    k_attnC<<<dim3(NC, H_), blk, 0, stream>>>(qb, kb, vb, Mem, ybuf);
    k_gemm128<E_RES><<<dim3(4, 32), blk, 0, stream>>>(
        ybuf, WoT + (size_t)l * DD, x, x, D_, D_, D_, D_);
    k_ln<<<dim3(NROW), dim3(128), 0, stream>>>(x, ln2g + l * D_, ln2b + l * D_, h);
    k_gemm256<E_GELU><<<dim3(24, 16), dim3(512), 0, stream>>>(
        h, W1T + (size_t)l * NL_ * HID_ * D_, b1 + (size_t)l * NL_ * HID_, hmid,
        D_, NL_ * HID_, NL_ * HID_);
    k_gemm128<E_PART><<<dim3(4, 32, 3), blk, 0, stream>>>(
        hmid, W2cat + (size_t)l * D_ * NL_ * HID_, bsum, parts,
        2048, NL_ * HID_, D_, D_);
    const float* gn = (l < 3) ? (ln1g + (l + 1) * D_) : lnfg;
    const float* bn = (l < 3) ? (ln1b + (l + 1) * D_) : lnfb;
    k_cmsred_ln<<<dim3(NROW / 2), blk, 0, stream>>>(x, parts, bsum + l * D_, gn, bn, h);
  }
  k_gemm256<E_F32><<<dim3(125, 16), dim3(512), 0, stream>>>(
      h, embB, bsum, d_out, D_, V_, V_);
}